// Round 4
// baseline (21659.962 us; speedup 1.0000x reference)
//
#include <hip/hip_runtime.h>

// ---------------------------------------------------------------------------
// Round 4: DIAGNOSTIC-SIMPLE implementation. fp32 in / fp32 out (established
// R3: bf16 reads -> NaN => inputs fp32; R1/R2 finite fp32 reads => out fp32).
// One thread per output element, no LDS, no tiling. Goal: correctness anchor.
// ---------------------------------------------------------------------------

template<int IC, int OC, int H, int W>
__global__ __launch_bounds__(256) void conv3x3_relu_simple(
    const float* __restrict__ in, const float* __restrict__ wgt,
    const float* __restrict__ bias, float* __restrict__ out, int B)
{
    long idx = (long)blockIdx.x * 256 + threadIdx.x;
    long total = (long)B * OC * H * W;
    if (idx >= total) return;
    int x  = (int)(idx % W);
    int y  = (int)((idx / W) % H);
    int oc = (int)((idx / ((long)W * H)) % OC);
    int b  = (int)(idx / ((long)W * H * OC));

    float acc = bias[oc];
    for (int ic = 0; ic < IC; ++ic) {
        const float* ip = in + ((long)(b * IC + ic)) * H * W;
        const float* wp = wgt + ((long)(oc * IC + ic)) * 9;
#pragma unroll
        for (int ky = 0; ky < 3; ++ky) {
            int yy = y + ky - 1;
            if (yy < 0 || yy >= H) continue;
#pragma unroll
            for (int kx = 0; kx < 3; ++kx) {
                int xx = x + kx - 1;
                if (xx < 0 || xx >= W) continue;
                acc += ip[yy * W + xx] * wp[ky * 3 + kx];
            }
        }
    }
    out[idx] = acc > 0.f ? acc : 0.f;
}

__global__ __launch_bounds__(256) void maxpool2x2(
    const float* __restrict__ in, float* __restrict__ out,
    int total, int Hout, int Wout)
{
    int idx = blockIdx.x * 256 + threadIdx.x;
    if (idx >= total) return;
    int x  = idx % Wout;
    int t  = idx / Wout;
    int y  = t % Hout;
    int bc = t / Hout;                  // fused b*C + c
    int Win = 2 * Wout;
    const float* p = in + ((long)(bc * (2 * Hout) + 2 * y) * Win) + 2 * x;
    float m0 = fmaxf(p[0], p[1]);
    float m1 = fmaxf(p[Win], p[Win + 1]);
    out[idx] = fmaxf(m0, m1);
}

// One THREAD per (sample, class) — maximally simple.
__global__ __launch_bounds__(256) void classifier5_simple(
    const float* __restrict__ feat, const int* __restrict__ tid_arr,
    const float* __restrict__ cw, const float* __restrict__ cb,
    float* __restrict__ out, int B)
{
    int idx = blockIdx.x * 256 + threadIdx.x;
    if (idx >= B * 5) return;
    int b = idx / 5;
    int c = idx % 5;
    int t = tid_arr[b];
    const float* wrow = cw + (size_t)(t * 5 + c) * 4096;
    const float* f    = feat + (size_t)b * 4096;
    float s = cb[t * 5 + c];
    for (int i = 0; i < 4096; ++i)
        s += wrow[i] * f[i];
    out[idx] = s;
}

extern "C" void kernel_launch(void* const* d_in, const int* in_sizes, int n_in,
                              void* d_out, int out_size, void* d_ws, size_t ws_size,
                              hipStream_t stream)
{
    const float* x   = (const float*)d_in[0];
    const int*   tid = (const int*)d_in[1];
    const float* w0 = (const float*)d_in[2];  const float* b0 = (const float*)d_in[3];
    const float* w1 = (const float*)d_in[4];  const float* b1 = (const float*)d_in[5];
    const float* w2 = (const float*)d_in[6];  const float* b2 = (const float*)d_in[7];
    const float* w3 = (const float*)d_in[8];  const float* b3 = (const float*)d_in[9];
    const float* w4 = (const float*)d_in[10]; const float* b4 = (const float*)d_in[11];
    const float* w5 = (const float*)d_in[12]; const float* b5 = (const float*)d_in[13];
    const float* cw = (const float*)d_in[14];
    const float* cb = (const float*)d_in[15];
    float* outp = (float*)d_out;

    const int B = in_sizes[0] / (3 * 32 * 32);   // 512

    // Per-sample workspace: two ping-pong fp32 buffers of 64*32*32 floats.
    const size_t per_sample = (size_t)2 * 64 * 32 * 32 * sizeof(float);  // 512 KiB
    int Bc = B;
    while (Bc > 1 && (size_t)Bc * per_sample > ws_size) Bc >>= 1;

    float* bufA = (float*)d_ws;
    float* bufB = bufA + (size_t)Bc * 64 * 32 * 32;

    for (int cb0 = 0; cb0 < B; cb0 += Bc) {
        const float* xc = x + (size_t)cb0 * 3 * 32 * 32;
        const int* tidc = tid + cb0;
        float* outc = outp + (size_t)cb0 * 5;

        long n;
        // conv0: 3->64 @32x32
        n = (long)Bc * 64 * 32 * 32;
        conv3x3_relu_simple<3, 64, 32, 32><<<(int)((n + 255) / 256), 256, 0, stream>>>(xc, w0, b0, bufA, Bc);
        // conv1: 64->64 @32x32
        conv3x3_relu_simple<64, 64, 32, 32><<<(int)((n + 255) / 256), 256, 0, stream>>>(bufA, w1, b1, bufB, Bc);
        // pool -> 16x16
        maxpool2x2<<<(Bc * 64 * 16 * 16 + 255) / 256, 256, 0, stream>>>(bufB, bufA, Bc * 64 * 16 * 16, 16, 16);
        // conv2: 64->128 @16x16
        n = (long)Bc * 128 * 16 * 16;
        conv3x3_relu_simple<64, 128, 16, 16><<<(int)((n + 255) / 256), 256, 0, stream>>>(bufA, w2, b2, bufB, Bc);
        // conv3: 128->128 @16x16
        conv3x3_relu_simple<128, 128, 16, 16><<<(int)((n + 255) / 256), 256, 0, stream>>>(bufB, w3, b3, bufA, Bc);
        // pool -> 8x8
        maxpool2x2<<<(Bc * 128 * 8 * 8 + 255) / 256, 256, 0, stream>>>(bufA, bufB, Bc * 128 * 8 * 8, 8, 8);
        // conv4: 128->256 @8x8
        n = (long)Bc * 256 * 8 * 8;
        conv3x3_relu_simple<128, 256, 8, 8><<<(int)((n + 255) / 256), 256, 0, stream>>>(bufB, w4, b4, bufA, Bc);
        // conv5: 256->256 @8x8
        conv3x3_relu_simple<256, 256, 8, 8><<<(int)((n + 255) / 256), 256, 0, stream>>>(bufA, w5, b5, bufB, Bc);
        // pool -> 4x4  => feat [Bc, 4096] (NCHW flatten)
        maxpool2x2<<<(Bc * 256 * 4 * 4 + 255) / 256, 256, 0, stream>>>(bufB, bufA, Bc * 256 * 4 * 4, 4, 4);
        // classifier
        classifier5_simple<<<(Bc * 5 + 255) / 256, 256, 0, stream>>>(bufA, tidc, cw, cb, outc, Bc);
    }
}

// Round 5
// 483.167 us; speedup vs baseline: 44.8291x; 44.8291x over previous
//
#include <hip/hip_runtime.h>

// ---------------------------------------------------------------------------
// Round 5: bf16 MFMA implicit-GEMM convs (NHWC bf16 activations), fp32 conv0,
// NHWC bf16 maxpool, task-indexed classifier. fp32 in / fp32 out.
// GEMM per conv layer: D[oc][px] = sum_k A[oc][k] * B[k][px],
//   k = (icb*32 ic-chunk) x 9 kernel taps; A = wT[kykx][oc][ic] bf16 (global),
//   B = im2col from LDS-staged NHWC tile (pad 32->40 hw rows: conflict-free).
// mfma_f32_16x16x32_bf16: A lane(m=lane&15) k=quad*8+j; B lane(n=lane&15)
// k=quad*8+j; D lane holds rows quad*4+r (=oc, consecutive), col lane&15 (=px).
// ---------------------------------------------------------------------------

typedef __attribute__((ext_vector_type(8))) short short8;
typedef __attribute__((ext_vector_type(4))) float floatx4;
typedef unsigned int uint;
typedef unsigned short ushort;

__device__ __forceinline__ ushort f2bf(float f) {
    uint u = __float_as_uint(f);
    return (ushort)((u + 0x7fffu + ((u >> 16) & 1u)) >> 16);
}
__device__ __forceinline__ float bf2f(ushort h) {
    return __uint_as_float(((uint)h) << 16);
}

// ---------------- weight transform: w[OC][IC][3][3] fp32 -> wT[9][OC][IC] bf16
__global__ __launch_bounds__(256) void wtransform(
    const float* __restrict__ src, short* __restrict__ dst, int OC, int IC)
{
    int n = 9 * OC * IC;
    int idx = blockIdx.x * 256 + threadIdx.x;
    if (idx >= n) return;
    int kk = idx / (OC * IC);
    int r  = idx - kk * (OC * IC);
    int oc = r / IC;
    int ic = r - oc * IC;
    dst[idx] = (short)f2bf(src[((long)oc * IC + ic) * 9 + kk]);
}

// ---------------- conv0: 3->64 @32x32, fp32 direct, NCHW fp32 in, NHWC bf16 out
__global__ __launch_bounds__(256) void conv0_k(
    const float* __restrict__ x, const float* __restrict__ w0,
    const float* __restrict__ b0, ushort* __restrict__ out)
{
    __shared__ float s_in[3][34][34];
    __shared__ float s_w[27][64];
    __shared__ float s_b[64];
    const int tid = threadIdx.x;
    const int b   = blockIdx.x;

    for (int idx = tid; idx < 3 * 34 * 34; idx += 256) {
        int c  = idx / (34 * 34);
        int r  = idx - c * 34 * 34;
        int ry = r / 34, rx = r - ry * 34;
        int gy = ry - 1, gx = rx - 1;
        float v = 0.f;
        if (gy >= 0 && gy < 32 && gx >= 0 && gx < 32)
            v = x[(((long)b * 3 + c) * 32 + gy) * 32 + gx];
        s_in[c][ry][rx] = v;
    }
    for (int idx = tid; idx < 27 * 64; idx += 256) {
        int j = idx >> 6, oc = idx & 63;
        s_w[j][oc] = w0[oc * 27 + j];
    }
    if (tid < 64) s_b[tid] = b0[tid];
    __syncthreads();

    for (int p = tid; p < 1024; p += 256) {
        int y = p >> 5, xx = p & 31;
        float iv[27];
#pragma unroll
        for (int c = 0; c < 3; ++c)
#pragma unroll
            for (int ky = 0; ky < 3; ++ky)
#pragma unroll
                for (int kx = 0; kx < 3; ++kx)
                    iv[c * 9 + ky * 3 + kx] = s_in[c][y + ky][xx + kx];
        ushort ov[64];
#pragma unroll 8
        for (int oc = 0; oc < 64; ++oc) {
            float acc = s_b[oc];
#pragma unroll
            for (int j = 0; j < 27; ++j) acc += iv[j] * s_w[j][oc];
            ov[oc] = f2bf(acc > 0.f ? acc : 0.f);
        }
        ushort* dst = out + ((long)b * 1024 + p) * 64;
#pragma unroll
        for (int k = 0; k < 8; ++k)
            *(uint4*)(dst + k * 8) = *(uint4*)(ov + k * 8);
    }
}

// ---------------- MFMA conv3x3+ReLU, NHWC bf16 in/out
// Block: ROWS consecutive rows of one sample. 4 waves = OCGROUPS x PXG.
// Wave: 4 m-frags (64 oc) x NFRAG n-frags (NFRAG*16 px).
template<int IC, int OC, int H, int W, int ROWS, int NFRAG, int OCGROUPS>
__global__ __launch_bounds__(256, 2) void conv3x3_mfma(
    const ushort* __restrict__ act_in,  // [B][H][W][IC] bf16
    const short*  __restrict__ wT,      // [9][OC][IC] bf16
    const float*  __restrict__ bias,    // [OC] fp32
    ushort* __restrict__ act_out)       // [B][H][W][OC] bf16
{
    constexpr int PXG  = 4 / OCGROUPS;
    constexpr int WPAD = W + 2;
    constexpr int RPAD = ROWS + 2;
    constexpr int LROW = 40;            // 32 ic + 8 pad (halfwords)
    constexpr int SEGS = H / ROWS;
    static_assert(PXG * NFRAG * 16 == ROWS * W, "px tiling mismatch");

    __shared__ ushort s_act[RPAD * WPAD * LROW];

    const int tid  = threadIdx.x;
    const int wv   = tid >> 6;
    const int lane = tid & 63;
    const int quad = lane >> 4;
    const int l16  = lane & 15;

    const int b   = blockIdx.x / SEGS;
    const int r0  = (blockIdx.x - b * SEGS) * ROWS;
    const int ocg = wv % OCGROUPS;
    const int pxg = wv / OCGROUPS;

    floatx4 acc[4][NFRAG];
#pragma unroll
    for (int i = 0; i < 4; ++i)
#pragma unroll
        for (int t = 0; t < NFRAG; ++t) acc[i][t] = (floatx4)0.f;

    int bbase[NFRAG];
#pragma unroll
    for (int t = 0; t < NFRAG; ++t) {
        int pxl = pxg * (NFRAG * 16) + t * 16 + l16;
        int py = pxl / W, px = pxl - py * W;
        bbase[t] = (py * WPAD + px) * LROW + quad * 8;
    }
    const long gpix0 = ((long)b * H + r0) * W;

    for (int icb = 0; icb < IC / 32; ++icb) {
        __syncthreads();
        constexpr int UNITS = RPAD * WPAD;
        for (int u = tid; u < UNITS * 4; u += 256) {
            int unit = u >> 2, sub = u & 3;
            int ry = unit / WPAD, cx = unit - ry * WPAD;
            int gy = r0 + ry - 1, gx = cx - 1;
            uint4 val = make_uint4(0, 0, 0, 0);
            if (gy >= 0 && gy < H && gx >= 0 && gx < W) {
                long src = (((long)b * H + gy) * W + gx) * IC + icb * 32 + sub * 8;
                val = *(const uint4*)(act_in + src);
            }
            *(uint4*)(&s_act[unit * LROW + sub * 8]) = val;
        }
        __syncthreads();

#pragma unroll
        for (int kk = 0; kk < 9; ++kk) {
            const int ky = kk / 3, kx = kk - ky * 3;
            short8 afr[4];
#pragma unroll
            for (int i = 0; i < 4; ++i) {
                int oc = ocg * 64 + i * 16 + l16;
                long off = ((long)kk * OC + oc) * IC + icb * 32 + quad * 8;
                afr[i] = *(const short8*)(wT + off);
            }
            short8 bfr[NFRAG];
            const int koff = (ky * WPAD + kx) * LROW;
#pragma unroll
            for (int t = 0; t < NFRAG; ++t)
                bfr[t] = *(const short8*)(&s_act[bbase[t] + koff]);
#pragma unroll
            for (int i = 0; i < 4; ++i)
#pragma unroll
                for (int t = 0; t < NFRAG; ++t)
                    acc[i][t] = __builtin_amdgcn_mfma_f32_16x16x32_bf16(
                        afr[i], bfr[t], acc[i][t], 0, 0, 0);
        }
    }

    // epilogue: bias + ReLU + bf16 NHWC store (4 consecutive oc per lane)
#pragma unroll
    for (int i = 0; i < 4; ++i) {
        int oc0 = ocg * 64 + i * 16 + quad * 4;
        float4 bv = *(const float4*)(bias + oc0);
#pragma unroll
        for (int t = 0; t < NFRAG; ++t) {
            int pxl = pxg * (NFRAG * 16) + t * 16 + l16;
            long dst = (gpix0 + pxl) * OC + oc0;
            float v0 = acc[i][t][0] + bv.x;
            float v1 = acc[i][t][1] + bv.y;
            float v2 = acc[i][t][2] + bv.z;
            float v3 = acc[i][t][3] + bv.w;
            ushort o[4];
            o[0] = f2bf(v0 > 0.f ? v0 : 0.f);
            o[1] = f2bf(v1 > 0.f ? v1 : 0.f);
            o[2] = f2bf(v2 > 0.f ? v2 : 0.f);
            o[3] = f2bf(v3 > 0.f ? v3 : 0.f);
            *(uint2*)(act_out + dst) = *(uint2*)o;
        }
    }
}

// ---------------- maxpool 2x2 NHWC bf16 (post-ReLU: integer max is valid)
template<int C>
__global__ __launch_bounds__(256) void maxpool_nhwc(
    const ushort* __restrict__ in, ushort* __restrict__ out,
    int total8, int HO, int WO)
{
    int idx = blockIdx.x * 256 + threadIdx.x;
    if (idx >= total8) return;
    int c8 = idx % (C / 8);
    int p  = idx / (C / 8);
    int xo = p % WO;
    int t  = p / WO;
    int yo = t % HO;
    int b  = t / HO;
    const int WI = 2 * WO;
    const ushort* base = in + ((((long)b * 2 * HO + 2 * yo) * WI + 2 * xo) * C) + c8 * 8;
    uint4 q0 = *(const uint4*)(base);
    uint4 q1 = *(const uint4*)(base + C);
    uint4 q2 = *(const uint4*)(base + (long)WI * C);
    uint4 q3 = *(const uint4*)(base + (long)WI * C + C);
    const ushort* a0 = (const ushort*)&q0;
    const ushort* a1 = (const ushort*)&q1;
    const ushort* a2 = (const ushort*)&q2;
    const ushort* a3 = (const ushort*)&q3;
    ushort r[8];
#pragma unroll
    for (int j = 0; j < 8; ++j) {
        ushort m0 = a0[j] > a1[j] ? a0[j] : a1[j];
        ushort m1 = a2[j] > a3[j] ? a2[j] : a3[j];
        r[j] = m0 > m1 ? m0 : m1;
    }
    *(uint4*)(out + (long)p * C + c8 * 8) = *(uint4*)r;
}

// ---------------- classifier: wave per (b, class); feat NHWC [b][4][4][256]
// reference flatten d = c*16 + (y*4+x)  ->  feat[b][p][c], p = d&15, c = d>>4
__global__ __launch_bounds__(256) void classifier_k(
    const ushort* __restrict__ feat, const int* __restrict__ tids,
    const float* __restrict__ cw, const float* __restrict__ cb,
    float* __restrict__ out, int B)
{
    int g = blockIdx.x * 256 + threadIdx.x;
    int wid = g >> 6, lane = g & 63;
    if (wid >= B * 5) return;
    int b = wid / 5, c = wid - b * 5;
    int t = tids[b];
    const float* wrow = cw + (long)(t * 5 + c) * 4096;
    const ushort* f = feat + (long)b * 4096;
    float s = 0.f;
#pragma unroll 4
    for (int d = lane; d < 4096; d += 64) {
        int ch = d >> 4, p = d & 15;
        s += wrow[d] * bf2f(f[p * 256 + ch]);
    }
#pragma unroll
    for (int off = 32; off > 0; off >>= 1) s += __shfl_down(s, off, 64);
    if (lane == 0) out[wid] = s + cb[t * 5 + c];
}

// ---------------------------------------------------------------------------
extern "C" void kernel_launch(void* const* d_in, const int* in_sizes, int n_in,
                              void* d_out, int out_size, void* d_ws, size_t ws_size,
                              hipStream_t stream)
{
    const float* x   = (const float*)d_in[0];
    const int*   tid = (const int*)d_in[1];
    const float* w0 = (const float*)d_in[2];  const float* b0 = (const float*)d_in[3];
    const float* w1 = (const float*)d_in[4];  const float* b1 = (const float*)d_in[5];
    const float* w2 = (const float*)d_in[6];  const float* b2 = (const float*)d_in[7];
    const float* w3 = (const float*)d_in[8];  const float* b3 = (const float*)d_in[9];
    const float* w4 = (const float*)d_in[10]; const float* b4 = (const float*)d_in[11];
    const float* w5 = (const float*)d_in[12]; const float* b5 = (const float*)d_in[13];
    const float* cw = (const float*)d_in[14];
    const float* cb = (const float*)d_in[15];
    float* outp = (float*)d_out;

    const int B = in_sizes[0] / (3 * 32 * 32);   // 512

    // ---- ws layout (halfword units) ----
    short* wt1 = (short*)d_ws;                    // 9*64*64    = 36864
    short* wt2 = wt1 + 36864;                     // 9*128*64   = 73728
    short* wt3 = wt2 + 73728;                     // 9*128*128  = 147456
    short* wt4 = wt3 + 147456;                    // 9*256*128  = 294912
    short* wt5 = wt4 + 294912;                    // 9*256*256  = 589824
    const size_t WT_HW = 1142784;                 // total weight halfwords
    const size_t fixed_bytes = WT_HW * 2;

    // activation ping-pong (bf16): per sample max 32*32*64 = 65536 halfwords
    int Bc = B;
    while (Bc > 1 && fixed_bytes + (size_t)Bc * 2 * 65536 * 2 > ws_size) Bc >>= 1;

    ushort* bufA = (ushort*)((short*)d_ws + WT_HW);
    ushort* bufB = bufA + (size_t)Bc * 65536;

    // ---- weight transforms (once per launch) ----
    wtransform<<<(9 * 64 * 64 + 255) / 256, 256, 0, stream>>>(w1, wt1, 64, 64);
    wtransform<<<(9 * 128 * 64 + 255) / 256, 256, 0, stream>>>(w2, wt2, 128, 64);
    wtransform<<<(9 * 128 * 128 + 255) / 256, 256, 0, stream>>>(w3, wt3, 128, 128);
    wtransform<<<(9 * 256 * 128 + 255) / 256, 256, 0, stream>>>(w4, wt4, 256, 128);
    wtransform<<<(9 * 256 * 256 + 255) / 256, 256, 0, stream>>>(w5, wt5, 256, 256);

    for (int cb0 = 0; cb0 < B; cb0 += Bc) {
        const float* xc = x + (size_t)cb0 * 3 * 32 * 32;
        const int* tidc = tid + cb0;
        float* outc = outp + (size_t)cb0 * 5;

        // conv0: fp32 direct -> NHWC bf16 [Bc,32,32,64]
        conv0_k<<<Bc, 256, 0, stream>>>(xc, w0, b0, bufA);
        // conv1: 64->64 @32x32   (2 blocks/sample: 16 rows each)
        conv3x3_mfma<64, 64, 32, 32, 16, 8, 1><<<Bc * 2, 256, 0, stream>>>(bufA, wt1, b1, bufB);
        // pool -> [Bc,16,16,64]
        maxpool_nhwc<64><<<(Bc * 16 * 16 * 8 + 255) / 256, 256, 0, stream>>>(bufB, bufA, Bc * 16 * 16 * 8, 16, 16);
        // conv2: 64->128 @16x16
        conv3x3_mfma<64, 128, 16, 16, 16, 8, 2><<<Bc, 256, 0, stream>>>(bufA, wt2, b2, bufB);
        // conv3: 128->128 @16x16
        conv3x3_mfma<128, 128, 16, 16, 16, 8, 2><<<Bc, 256, 0, stream>>>(bufB, wt3, b3, bufA);
        // pool -> [Bc,8,8,128]
        maxpool_nhwc<128><<<(Bc * 8 * 8 * 16 + 255) / 256, 256, 0, stream>>>(bufA, bufB, Bc * 8 * 8 * 16, 8, 8);
        // conv4: 128->256 @8x8
        conv3x3_mfma<128, 256, 8, 8, 8, 4, 4><<<Bc, 256, 0, stream>>>(bufB, wt4, b4, bufA);
        // conv5: 256->256 @8x8
        conv3x3_mfma<256, 256, 8, 8, 8, 4, 4><<<Bc, 256, 0, stream>>>(bufA, wt5, b5, bufB);
        // pool -> [Bc,4,4,256]
        maxpool_nhwc<256><<<(Bc * 4 * 4 * 32 + 255) / 256, 256, 0, stream>>>(bufB, bufA, Bc * 4 * 4 * 32, 4, 4);
        // classifier
        classifier_k<<<(Bc * 5 * 64 + 255) / 256, 256, 0, stream>>>(bufA, tidc, cw, cb, outc, Bc);
    }
}

// Round 6
// 482.977 us; speedup vs baseline: 44.8468x; 1.0004x over previous
//
#include <hip/hip_runtime.h>

// ---------------------------------------------------------------------------
// Round 6: all-MFMA convs. NHWC bf16 activations, fp32 accum, fp32 in/out.
// LDS B-tile layout is k-chunk-major: s_act[q][unit][8hw] (q = ic-octet) so
// every ds_read_b128 phase hits 16 consecutive 16B chunks = conflict-free
// (R5's row-pad-40 layout measured 4.9M SQ_LDS_BANK_CONFLICT = 8-way).
// conv0 (IC=3) is im2col'd to K=32 (27 taps + 5 zeros) and also runs MFMA.
// conv4/5 take 2 samples per block (NFRAG=8) to halve weight L2 refetch.
// ---------------------------------------------------------------------------

typedef __attribute__((ext_vector_type(8))) short short8;
typedef __attribute__((ext_vector_type(4))) float floatx4;
typedef unsigned int uint;
typedef unsigned short ushort;

__device__ __forceinline__ ushort f2bf(float f) {
    uint u = __float_as_uint(f);
    return (ushort)((u + 0x7fffu + ((u >> 16) & 1u)) >> 16);
}
__device__ __forceinline__ float bf2f(ushort h) {
    return __uint_as_float(((uint)h) << 16);
}

// ---------------- weight transform: w[OC][IC][3][3] fp32 -> wT[9][OC][IC] bf16
__global__ __launch_bounds__(256) void wtransform(
    const float* __restrict__ src, short* __restrict__ dst, int OC, int IC)
{
    int n = 9 * OC * IC;
    int idx = blockIdx.x * 256 + threadIdx.x;
    if (idx >= n) return;
    int kk = idx / (OC * IC);
    int r  = idx - kk * (OC * IC);
    int oc = r / IC;
    int ic = r - oc * IC;
    dst[idx] = (short)f2bf(src[((long)oc * IC + ic) * 9 + kk]);
}

// conv0 weights: w0[64][3][3][3] fp32 -> wT0[64][32] bf16, k = c*9+ky*3+kx, pad 0
__global__ __launch_bounds__(256) void wtransform0(
    const float* __restrict__ src, short* __restrict__ dst)
{
    int idx = blockIdx.x * 256 + threadIdx.x;
    if (idx >= 64 * 32) return;
    int oc = idx >> 5, k = idx & 31;
    dst[idx] = (k < 27) ? (short)f2bf(src[oc * 27 + k]) : (short)0;
}

// ---------------- conv0 MFMA: 3->64 @32x32, NCHW fp32 in, NHWC bf16 out
// Block = 16-row strip of one sample (512 px). K=32 im2col. 4 waves x 128 px.
__global__ __launch_bounds__(256, 2) void conv0_mfma(
    const float* __restrict__ x, const short* __restrict__ wT0,
    const float* __restrict__ b0, ushort* __restrict__ out)
{
    __shared__ float  s_x[3 * 18 * 34];        // haloed fp32 strip
    __shared__ ushort s_b[4 * 512 * 8];        // im2col [q][px][8]

    const int tid  = threadIdx.x;
    const int wv   = tid >> 6;
    const int lane = tid & 63;
    const int quad = lane >> 4;
    const int l16  = lane & 15;
    const int b    = blockIdx.x >> 1;
    const int r0   = (blockIdx.x & 1) * 16;

    // stage haloed input strip (fp32)
    for (int idx = tid; idx < 3 * 18 * 34; idx += 256) {
        int c   = idx / 612;
        int rem = idx - c * 612;
        int ry  = rem / 34, rx = rem - ry * 34;
        int gy  = r0 + ry - 1, gx = rx - 1;
        float v = 0.f;
        if (gy >= 0 && gy < 32 && gx >= 0 && gx < 32)
            v = x[(((long)b * 3 + c) * 32 + gy) * 32 + gx];
        s_x[idx] = v;
    }
    __syncthreads();

    // im2col: 2 px per thread, k = c*9 + ky*3 + kx (matches wT0), pad 27..31 = 0
#pragma unroll
    for (int rep = 0; rep < 2; ++rep) {
        int pxl = rep * 256 + tid;
        int py = pxl >> 5, px = pxl & 31;
        ushort v[32];
#pragma unroll
        for (int c = 0; c < 3; ++c)
#pragma unroll
            for (int ky = 0; ky < 3; ++ky)
#pragma unroll
                for (int kx = 0; kx < 3; ++kx)
                    v[c * 9 + ky * 3 + kx] = f2bf(s_x[c * 612 + (py + ky) * 34 + (px + kx)]);
#pragma unroll
        for (int k = 27; k < 32; ++k) v[k] = 0;
#pragma unroll
        for (int q = 0; q < 4; ++q)
            *(uint4*)(&s_b[(q * 512 + pxl) * 8]) = *(const uint4*)(v + q * 8);
    }
    __syncthreads();

    // MFMA: 4 m-frags (64 oc) x 8 n-frags (128 px per wave)
    floatx4 acc[4][8];
#pragma unroll
    for (int i = 0; i < 4; ++i)
#pragma unroll
        for (int t = 0; t < 8; ++t) acc[i][t] = (floatx4)0.f;

    short8 afr[4];
#pragma unroll
    for (int i = 0; i < 4; ++i)
        afr[i] = *(const short8*)(wT0 + (i * 16 + l16) * 32 + quad * 8);
#pragma unroll
    for (int t = 0; t < 8; ++t) {
        int pxl = wv * 128 + t * 16 + l16;
        short8 bfr = *(const short8*)(&s_b[(quad * 512 + pxl) * 8]);
#pragma unroll
        for (int i = 0; i < 4; ++i)
            acc[i][t] = __builtin_amdgcn_mfma_f32_16x16x32_bf16(afr[i], bfr, acc[i][t], 0, 0, 0);
    }

    // epilogue: bias + ReLU + NHWC bf16 store
#pragma unroll
    for (int i = 0; i < 4; ++i) {
        int oc0 = i * 16 + quad * 4;
        float4 bv = *(const float4*)(b0 + oc0);
#pragma unroll
        for (int t = 0; t < 8; ++t) {
            int pxl = wv * 128 + t * 16 + l16;
            int py = pxl >> 5, px = pxl & 31;
            long dst = (((long)b * 32 + r0 + py) * 32 + px) * 64 + oc0;
            float v0 = acc[i][t][0] + bv.x;
            float v1 = acc[i][t][1] + bv.y;
            float v2 = acc[i][t][2] + bv.z;
            float v3 = acc[i][t][3] + bv.w;
            ushort o[4];
            o[0] = f2bf(v0 > 0.f ? v0 : 0.f);
            o[1] = f2bf(v1 > 0.f ? v1 : 0.f);
            o[2] = f2bf(v2 > 0.f ? v2 : 0.f);
            o[3] = f2bf(v3 > 0.f ? v3 : 0.f);
            *(uint2*)(out + dst) = *(uint2*)o;
        }
    }
}

// ---------------- MFMA conv3x3+ReLU, NHWC bf16 in/out, k-chunk-major LDS
// Block: NSAMP samples x ROWS rows. 4 waves = OCGROUPS x PXG.
template<int IC, int OC, int H, int W, int ROWS, int NSAMP, int NFRAG, int OCGROUPS>
__global__ __launch_bounds__(256, 2) void conv3x3_mfma(
    const ushort* __restrict__ act_in,  // [B][H][W][IC] bf16
    const short*  __restrict__ wT,      // [9][OC][IC] bf16
    const float*  __restrict__ bias,    // [OC] fp32
    ushort* __restrict__ act_out)       // [B][H][W][OC] bf16
{
    constexpr int PXG   = 4 / OCGROUPS;
    constexpr int WPAD  = W + 2;
    constexpr int RPAD  = ROWS + 2;
    constexpr int SUNIT = RPAD * WPAD;          // units per sample
    constexpr int UNITS = NSAMP * SUNIT;
    constexpr int SEGS  = H / ROWS;
    static_assert(PXG * NFRAG * 16 == NSAMP * ROWS * W, "px tiling mismatch");

    __shared__ ushort s_act[4 * UNITS * 8];     // [q][unit][8hw]

    const int tid  = threadIdx.x;
    const int wv   = tid >> 6;
    const int lane = tid & 63;
    const int quad = lane >> 4;
    const int l16  = lane & 15;

    const int bs  = blockIdx.x / SEGS;
    const int seg = blockIdx.x - bs * SEGS;
    const int b0  = bs * NSAMP;
    const int r0  = seg * ROWS;
    const int ocg = wv % OCGROUPS;
    const int pxg = wv / OCGROUPS;

    floatx4 acc[4][NFRAG];
#pragma unroll
    for (int i = 0; i < 4; ++i)
#pragma unroll
        for (int t = 0; t < NFRAG; ++t) acc[i][t] = (floatx4)0.f;

    // per-lane B base: hw address of (quad, pixel-unit), taps add (ky*WPAD+kx)*8
    int bbase[NFRAG];
#pragma unroll
    for (int t = 0; t < NFRAG; ++t) {
        int pxl = pxg * (NFRAG * 16) + t * 16 + l16;
        int s   = pxl / (ROWS * W);
        int p2  = pxl - s * (ROWS * W);
        int py  = p2 / W, px = p2 - py * W;
        bbase[t] = (quad * UNITS + s * SUNIT + py * WPAD + px) * 8;
    }

    for (int icb = 0; icb < IC / 32; ++icb) {
        __syncthreads();
        for (int u = tid; u < UNITS * 4; u += 256) {
            int unit = u >> 2, sub = u & 3;
            int s    = unit / SUNIT;
            int rem  = unit - s * SUNIT;
            int ry   = rem / WPAD, cx = rem - ry * WPAD;
            int gy   = r0 + ry - 1, gx = cx - 1;
            uint4 val = make_uint4(0, 0, 0, 0);
            if (gy >= 0 && gy < H && gx >= 0 && gx < W) {
                long src = (((long)(b0 + s) * H + gy) * W + gx) * IC + icb * 32 + sub * 8;
                val = *(const uint4*)(act_in + src);
            }
            *(uint4*)(&s_act[(sub * UNITS + unit) * 8]) = val;
        }
        __syncthreads();

#pragma unroll
        for (int kk = 0; kk < 9; ++kk) {
            const int ky = kk / 3, kx = kk - ky * 3;
            const int kuoff = (ky * WPAD + kx) * 8;
            short8 afr[4];
#pragma unroll
            for (int i = 0; i < 4; ++i) {
                int oc = ocg * 64 + i * 16 + l16;
                long off = ((long)kk * OC + oc) * IC + icb * 32 + quad * 8;
                afr[i] = *(const short8*)(wT + off);
            }
            short8 bfr[NFRAG];
#pragma unroll
            for (int t = 0; t < NFRAG; ++t)
                bfr[t] = *(const short8*)(&s_act[bbase[t] + kuoff]);
#pragma unroll
            for (int i = 0; i < 4; ++i)
#pragma unroll
                for (int t = 0; t < NFRAG; ++t)
                    acc[i][t] = __builtin_amdgcn_mfma_f32_16x16x32_bf16(
                        afr[i], bfr[t], acc[i][t], 0, 0, 0);
        }
    }

    // epilogue: bias + ReLU + bf16 NHWC store (4 consecutive oc per lane)
#pragma unroll
    for (int i = 0; i < 4; ++i) {
        int oc0 = ocg * 64 + i * 16 + quad * 4;
        float4 bv = *(const float4*)(bias + oc0);
#pragma unroll
        for (int t = 0; t < NFRAG; ++t) {
            int pxl = pxg * (NFRAG * 16) + t * 16 + l16;
            int s   = pxl / (ROWS * W);
            int p2  = pxl - s * (ROWS * W);
            int py  = p2 / W, px = p2 - py * W;
            long dst = (((long)(b0 + s) * H + r0 + py) * W + px) * OC + oc0;
            float v0 = acc[i][t][0] + bv.x;
            float v1 = acc[i][t][1] + bv.y;
            float v2 = acc[i][t][2] + bv.z;
            float v3 = acc[i][t][3] + bv.w;
            ushort o[4];
            o[0] = f2bf(v0 > 0.f ? v0 : 0.f);
            o[1] = f2bf(v1 > 0.f ? v1 : 0.f);
            o[2] = f2bf(v2 > 0.f ? v2 : 0.f);
            o[3] = f2bf(v3 > 0.f ? v3 : 0.f);
            *(uint2*)(act_out + dst) = *(uint2*)o;
        }
    }
}

// ---------------- maxpool 2x2 NHWC bf16 (post-ReLU: integer max is valid)
template<int C>
__global__ __launch_bounds__(256) void maxpool_nhwc(
    const ushort* __restrict__ in, ushort* __restrict__ out,
    int total8, int HO, int WO)
{
    int idx = blockIdx.x * 256 + threadIdx.x;
    if (idx >= total8) return;
    int c8 = idx % (C / 8);
    int p  = idx / (C / 8);
    int xo = p % WO;
    int t  = p / WO;
    int yo = t % HO;
    int b  = t / HO;
    const int WI = 2 * WO;
    const ushort* base = in + ((((long)b * 2 * HO + 2 * yo) * WI + 2 * xo) * C) + c8 * 8;
    uint4 q0 = *(const uint4*)(base);
    uint4 q1 = *(const uint4*)(base + C);
    uint4 q2 = *(const uint4*)(base + (long)WI * C);
    uint4 q3 = *(const uint4*)(base + (long)WI * C + C);
    const ushort* a0 = (const ushort*)&q0;
    const ushort* a1 = (const ushort*)&q1;
    const ushort* a2 = (const ushort*)&q2;
    const ushort* a3 = (const ushort*)&q3;
    ushort r[8];
#pragma unroll
    for (int j = 0; j < 8; ++j) {
        ushort m0 = a0[j] > a1[j] ? a0[j] : a1[j];
        ushort m1 = a2[j] > a3[j] ? a2[j] : a3[j];
        r[j] = m0 > m1 ? m0 : m1;
    }
    *(uint4*)(out + (long)p * C + c8 * 8) = *(uint4*)r;
}

// ---------------- classifier: wave per (b, class); feat NHWC [b][4][4][256]
// reference flatten d = ch*16 + (y*4+x)  ->  feat[b][p][ch], p = d&15, ch = d>>4
__global__ __launch_bounds__(256) void classifier_k(
    const ushort* __restrict__ feat, const int* __restrict__ tids,
    const float* __restrict__ cw, const float* __restrict__ cb,
    float* __restrict__ out, int B)
{
    int g = blockIdx.x * 256 + threadIdx.x;
    int wid = g >> 6, lane = g & 63;
    if (wid >= B * 5) return;
    int b = wid / 5, c = wid - b * 5;
    int t = tids[b];
    const float* wrow = cw + (long)(t * 5 + c) * 4096;
    const ushort* f = feat + (long)b * 4096;
    float s = 0.f;
#pragma unroll 4
    for (int d = lane; d < 4096; d += 64) {
        int ch = d >> 4, p = d & 15;
        s += wrow[d] * bf2f(f[p * 256 + ch]);
    }
#pragma unroll
    for (int off = 32; off > 0; off >>= 1) s += __shfl_down(s, off, 64);
    if (lane == 0) out[wid] = s + cb[t * 5 + c];
}

// ---------------------------------------------------------------------------
extern "C" void kernel_launch(void* const* d_in, const int* in_sizes, int n_in,
                              void* d_out, int out_size, void* d_ws, size_t ws_size,
                              hipStream_t stream)
{
    const float* x   = (const float*)d_in[0];
    const int*   tid = (const int*)d_in[1];
    const float* w0 = (const float*)d_in[2];  const float* b0 = (const float*)d_in[3];
    const float* w1 = (const float*)d_in[4];  const float* b1 = (const float*)d_in[5];
    const float* w2 = (const float*)d_in[6];  const float* b2 = (const float*)d_in[7];
    const float* w3 = (const float*)d_in[8];  const float* b3 = (const float*)d_in[9];
    const float* w4 = (const float*)d_in[10]; const float* b4 = (const float*)d_in[11];
    const float* w5 = (const float*)d_in[12]; const float* b5 = (const float*)d_in[13];
    const float* cw = (const float*)d_in[14];
    const float* cb = (const float*)d_in[15];
    float* outp = (float*)d_out;

    const int B = in_sizes[0] / (3 * 32 * 32);   // 512

    // ---- ws layout (halfword units) ----
    short* wt0 = (short*)d_ws;                    // 64*32      = 2048
    short* wt1 = wt0 + 2048;                      // 9*64*64    = 36864
    short* wt2 = wt1 + 36864;                     // 9*128*64   = 73728
    short* wt3 = wt2 + 73728;                     // 9*128*128  = 147456
    short* wt4 = wt3 + 147456;                    // 9*256*128  = 294912
    short* wt5 = wt4 + 294912;                    // 9*256*256  = 589824
    const size_t WT_HW = 2048 + 36864 + 73728 + 147456 + 294912 + 589824;
    const size_t fixed_bytes = WT_HW * 2;

    // activation ping-pong (bf16): per sample max 32*32*64 = 65536 hw per buffer
    int Bc = B;
    while (Bc > 2 && fixed_bytes + (size_t)Bc * 2 * 65536 * 2 > ws_size) Bc >>= 1;
    if (Bc < 2) Bc = 2;

    ushort* bufA = (ushort*)((short*)d_ws + WT_HW);
    ushort* bufB = bufA + (size_t)Bc * 65536;

    // ---- weight transforms (once per launch) ----
    wtransform0<<<(64 * 32 + 255) / 256, 256, 0, stream>>>(w0, wt0);
    wtransform<<<(9 * 64 * 64 + 255) / 256, 256, 0, stream>>>(w1, wt1, 64, 64);
    wtransform<<<(9 * 128 * 64 + 255) / 256, 256, 0, stream>>>(w2, wt2, 128, 64);
    wtransform<<<(9 * 128 * 128 + 255) / 256, 256, 0, stream>>>(w3, wt3, 128, 128);
    wtransform<<<(9 * 256 * 128 + 255) / 256, 256, 0, stream>>>(w4, wt4, 256, 128);
    wtransform<<<(9 * 256 * 256 + 255) / 256, 256, 0, stream>>>(w5, wt5, 256, 256);

    for (int cb0 = 0; cb0 < B; cb0 += Bc) {
        const float* xc = x + (size_t)cb0 * 3 * 32 * 32;
        const int* tidc = tid + cb0;
        float* outc = outp + (size_t)cb0 * 5;

        // conv0: 3->64 @32x32 MFMA (im2col K=32) -> NHWC bf16 [Bc,32,32,64]
        conv0_mfma<<<Bc * 2, 256, 0, stream>>>(xc, wt0, b0, bufA);
        // conv1: 64->64 @32x32   (2 strips/sample)
        conv3x3_mfma<64, 64, 32, 32, 16, 1, 8, 1><<<Bc * 2, 256, 0, stream>>>(bufA, wt1, b1, bufB);
        // pool -> [Bc,16,16,64]
        maxpool_nhwc<64><<<(Bc * 16 * 16 * 8 + 255) / 256, 256, 0, stream>>>(bufB, bufA, Bc * 16 * 16 * 8, 16, 16);
        // conv2: 64->128 @16x16
        conv3x3_mfma<64, 128, 16, 16, 16, 1, 8, 2><<<Bc, 256, 0, stream>>>(bufA, wt2, b2, bufB);
        // conv3: 128->128 @16x16
        conv3x3_mfma<128, 128, 16, 16, 16, 1, 8, 2><<<Bc, 256, 0, stream>>>(bufB, wt3, b3, bufA);
        // pool -> [Bc,8,8,128]
        maxpool_nhwc<128><<<(Bc * 8 * 8 * 16 + 255) / 256, 256, 0, stream>>>(bufA, bufB, Bc * 8 * 8 * 16, 8, 8);
        // conv4: 128->256 @8x8 (2 samples/block)
        conv3x3_mfma<128, 256, 8, 8, 8, 2, 8, 4><<<Bc / 2, 256, 0, stream>>>(bufB, wt4, b4, bufA);
        // conv5: 256->256 @8x8 (2 samples/block)
        conv3x3_mfma<256, 256, 8, 8, 8, 2, 8, 4><<<Bc / 2, 256, 0, stream>>>(bufA, wt5, b5, bufB);
        // pool -> [Bc,4,4,256]
        maxpool_nhwc<256><<<(Bc * 4 * 4 * 32 + 255) / 256, 256, 0, stream>>>(bufB, bufA, Bc * 4 * 4 * 32, 4, 4);
        // classifier
        classifier_k<<<(Bc * 5 * 64 + 255) / 256, 256, 0, stream>>>(bufA, tidc, cw, cb, outc, Bc);
    }
}